// Round 12
// baseline (153.336 us; speedup 1.0000x reference)
//
#include <hip/hip_runtime.h>

typedef unsigned short ushort_t;
typedef __attribute__((ext_vector_type(8)))  short  short8;
typedef __attribute__((ext_vector_type(8)))  ushort_t ushort8;
typedef __attribute__((ext_vector_type(16))) float  f32x16;

#define HWPX 16384
#define EPSV 0.001f

__device__ __forceinline__ ushort_t f2bf(float f) {
    unsigned u = __builtin_bit_cast(unsigned, f);
    unsigned r = u + 0x7FFFu + ((u >> 16) & 1u);   // round-to-nearest-even
    return (ushort_t)(r >> 16);
}

__device__ __forceinline__ unsigned cvt_pk(float a, float b) {
    unsigned r;
    asm("v_cvt_pk_bf16_f32 %0, %1, %2" : "=v"(r) : "v"(a), "v"(b));
    return r;   // lo = bf16(a), hi = bf16(b)
}

__device__ __forceinline__ void gld_lds16(const ushort_t* g, ushort_t* l) {
    __builtin_amdgcn_global_load_lds(
        (const __attribute__((address_space(1))) unsigned int*)g,
        (__attribute__((address_space(3))) unsigned int*)l, 16, 0, 0);
}

// ===================== Pass 1: coalesced stats + frag-ordered xb_t =========
// grid 512 = n(8) x g(8) x q(8); block 512 (8 waves). LDS 40KB. (unchanged;
// R9 probe: ~26us, ~80% of its HBM-read floor.)
__device__ __forceinline__ void stats_load(float4 (&buf)[4], const float* xbase,
                                           int w, int col4, int sub) {
    #pragma unroll
    for (int rr = 0; rr < 4; ++rr)
        buf[rr] = *(const float4*)(xbase + (size_t)(w + rr * 8) * HWPX + sub * 256 + col4 * 4);
}

template<bool XBF>
__global__ __launch_bounds__(512, 4) void k_stats(const float* __restrict__ x,
                                                  float* __restrict__ part,
                                                  ushort_t* __restrict__ xbt) {
    __shared__ char smraw[40960];         // union: tile(32KB) | redc(32KB); +redm 8KB
    ushort_t* tile = (ushort_t*)smraw;    // 2 x (32ch x 256px) bf16, swizzled
    float (*redc)[1024] = (float(*)[1024])smraw;
    float (*redm)[64] = (float(*)[64])(smraw + 32768);
    int b = blockIdx.x;
    int n = b >> 6, g = (b >> 3) & 7, q = b & 7;
    int t = threadIdx.x, w = t >> 6, l = t & 63;
    int lo = l & 31, hi = l >> 5, col4 = l;
    const float* xbase = x + ((size_t)(n * 256 + g * 32)) * HWPX + q * 2048;

    f32x16 acc = {};
    float sm[4] = {0.f, 0.f, 0.f, 0.f};
    float4 buf[4], nxt[4];

    stats_load(buf, xbase, w, col4, 0);
    #pragma unroll 1
    for (int s = 0; s < 8; ++s) {
        if (s < 7) stats_load(nxt, xbase, w, col4, s + 1);
        ushort_t* tl = tile + (s & 1) * 8192;
        #pragma unroll
        for (int rr = 0; rr < 4; ++rr) {
            float4 v = buf[rr];
            sm[rr] += v.x + v.y + v.z + v.w;
            uint2 u;
            u.x = cvt_pk(v.x, v.y);
            u.y = cvt_pk(v.z, v.w);
            int row = w + rr * 8;
            int idx = (row * 256 + col4 * 4) ^ ((row & 7) << 3);   // ushort-idx swizzle
            *(uint2*)&tl[idx] = u;
        }
        asm volatile("s_waitcnt lgkmcnt(0)" ::: "memory");
        __builtin_amdgcn_s_barrier();
        __builtin_amdgcn_sched_barrier(0);
        #pragma unroll
        for (int ks2 = 0; ks2 < 2; ++ks2) {
            int pidx = (lo * 256 + w * 32 + ks2 * 16 + hi * 8) ^ ((lo & 7) << 3);
            short8 f = *(const short8*)&tl[pidx];
            acc = __builtin_amdgcn_mfma_f32_32x32x16_bf16(f, f, acc, 0, 0, 0);
        }
        if (XBF) {
            int pb = q * 64 + s * 8 + w;
            #pragma unroll
            for (int h = 0; h < 2; ++h) {
                ushort8 o;
                #pragma unroll
                for (int j = 0; j < 8; ++j) {
                    int c = h * 16 + hi * 8 + j;
                    o[j] = tl[(c * 256 + w * 32 + lo) ^ ((c & 7) << 3)];
                }
                *(ushort8*)(xbt + ((((size_t)(n * 512 + pb)) * 16 + g * 2 + h) * 64 + l) * 8) = o;
            }
        }
        #pragma unroll
        for (int rr = 0; rr < 4; ++rr) buf[rr] = nxt[rr];
    }

    __syncthreads();
    #pragma unroll
    for (int r = 0; r < 16; ++r) redc[w][l * 16 + r] = acc[r];
    #pragma unroll
    for (int rr = 0; rr < 4; ++rr) redm[w + rr * 8][col4] = sm[rr];
    __syncthreads();

    for (int i = t; i < 1024; i += 512) {
        float v = 0.f;
        #pragma unroll
        for (int ww = 0; ww < 8; ++ww) v += redc[ww][i];
        int ll = i >> 4, r = i & 15;
        int row = (r & 3) + 8 * (r >> 2) + 4 * (ll >> 5);   // C/D layout 32x32 (m74/m101)
        int col = ll & 31;
        part[(size_t)b * 1056 + row * 32 + col] = v;
    }
    if (t < 32) {
        float v = 0.f;
        for (int c = 0; c < 64; ++c) v += redm[t][c];
        part[(size_t)b * 1056 + 1024 + t] = v;
    }
}

// ===================== Pass 2: reduce + LDS chol + back-subst compose ======
// (unchanged R11)
template<bool FRAG>
__global__ __launch_bounds__(256, 1) void k_prep(const float* __restrict__ part,
                                                 const float* __restrict__ conv_w,
                                                 const float* __restrict__ EK,
                                                 const int* __restrict__ cls_arr,
                                                 ushort_t* __restrict__ M_bf,
                                                 float* __restrict__ bp) {
    int bid = blockIdx.x;
    int n = bid >> 3, g = bid & 7;
    int t = threadIdx.x;
    __shared__ float cov[1024];
    __shared__ float sums[32];
    __shared__ float A[32][33];     // cov' -> L (lower, diag = sqrt)
    __shared__ float ml[32];
    __shared__ float cw[256][33];   // conv_w slice, padded

    for (int i = 0; i < 8; ++i) {
        int r = i * 32 + (t >> 3);
        float4 v = *(const float4*)(conv_w + r * 256 + g * 32 + (t & 7) * 4);
        #pragma unroll
        for (int e = 0; e < 4; ++e) cw[r][(t & 7) * 4 + e] = ((float*)&v)[e];
    }

    for (int i = t; i < 1024; i += 256) {
        float v = 0.f;
        for (int q = 0; q < 8; ++q) v += part[(size_t)(bid * 8 + q) * 1056 + i];
        cov[i] = v;
    }
    if (t < 32) {
        float v = 0.f;
        for (int q = 0; q < 8; ++q) v += part[(size_t)(bid * 8 + q) * 1056 + 1024 + t];
        sums[t] = v;
    }
    __syncthreads();

    const float invHW = 1.0f / (float)HWPX;
    #pragma unroll
    for (int p = 0; p < 4; ++p) {
        int idx = t + p * 256;
        int r = idx >> 5, c = idx & 31;
        float mr = sums[r] * invHW, mc = sums[c] * invHW;
        A[r][c] = (cov[idx] * invHW - mr * mc) * (1.0f - EPSV) + ((r == c) ? EPSV : 0.f);
    }
    if (t < 32) ml[t] = sums[t] * invHW;
    __syncthreads();

    for (int k = 0; k < 31; ++k) {
        float invd = 1.0f / A[k][k];
        #pragma unroll
        for (int p = 0; p < 4; ++p) {
            int idx = t + p * 256;
            int i = idx >> 5, j = idx & 31;
            if (j > k && j <= i) A[i][j] -= A[i][k] * A[j][k] * invd;
        }
        __syncthreads();
    }
    {
        float dsq[4];
        #pragma unroll
        for (int p = 0; p < 4; ++p) {
            int idx = t + p * 256;
            int j = idx & 31;
            dsq[p] = sqrtf(A[j][j]);
        }
        __syncthreads();
        #pragma unroll
        for (int p = 0; p < 4; ++p) {
            int idx = t + p * 256;
            int i = idx >> 5, j = idx & 31;
            if (j <= i) A[i][j] = A[i][j] / dsq[p];
        }
        __syncthreads();
    }

    int d = t;
    int cls = cls_arr[n];
    float a[32];
    #pragma unroll
    for (int c = 0; c < 32; ++c)
        a[c] = cw[d][c] + EK[(size_t)cls * 65536 + (size_t)(g * 32 + c) * 256 + d];

    float m[32];
    #pragma unroll
    for (int j = 31; j >= 0; --j) {
        float s = a[j];
        #pragma unroll
        for (int cp = j + 1; cp < 32; ++cp) s -= m[cp] * A[cp][j];   // broadcast reads
        m[j] = s / A[j][j];
    }

    float bpv = 0.f;
    ushort8 pk[4];
    #pragma unroll
    for (int cp = 0; cp < 32; ++cp) {
        bpv += m[cp] * ml[cp];
        pk[cp >> 3][cp & 7] = f2bf(m[cp]);
    }
    if (FRAG) {
        #pragma unroll
        for (int kk = 0; kk < 4; ++kk) {
            size_t u = (((size_t)(n * 8 + (d >> 5)) * 16) + g * 2 + (kk >> 1)) * 64
                       + (d & 31) + 32 * (kk & 1);
            *(ushort8*)(M_bf + u * 8) = pk[kk];
        }
    } else {
        ushort_t* dst = M_bf + ((size_t)(n * 256 + d)) * 256 + g * 32;
        #pragma unroll
        for (int k = 0; k < 4; ++k) *(ushort8*)(dst + k * 8) = pk[k];
    }
    bp[(size_t)(n * 8 + g) * 256 + d] = bpv;
}

// ===================== Pass 3 (fallback only): bias ========================
__global__ __launch_bounds__(256) void k_bias(const float* __restrict__ conv_b,
                                              const float* __restrict__ EB,
                                              const int* __restrict__ cls_arr,
                                              const float* __restrict__ bp,
                                              float* __restrict__ bias) {
    int n = blockIdx.x, d = threadIdx.x;
    int cls = cls_arr[n];
    float v = conv_b[d] + EB[cls * 256 + d];
    #pragma unroll
    for (int g = 0; g < 8; ++g) v -= bp[(size_t)(n * 8 + g) * 256 + d];
    bias[n * 256 + d] = v;
}

// ===================== Pass 4: out = M_t * xb_t + bias (fused, R8) =========
__global__ __launch_bounds__(512, 4) void k_gemm_s(const ushort_t* __restrict__ xbt,
                                                   const ushort_t* __restrict__ M_t,
                                                   const float* __restrict__ conv_b,
                                                   const float* __restrict__ EB,
                                                   const int* __restrict__ cls_arr,
                                                   const float* __restrict__ bp,
                                                   float* __restrict__ out) {
    __shared__ ushort_t bstage[24576];   // 3 x 16KB
    __shared__ float bias_l[256];
    int bid = blockIdx.x;
    int n = bid >> 6, pt = bid & 63;
    int t = threadIdx.x, w = t >> 6, l = t & 63, lo = l & 31, hi = l >> 5;
    int dblk = w * 32;

    if (t < 256) {
        int cls = cls_arr[n];
        float v = conv_b[t] + EB[cls * 256 + t];
        #pragma unroll
        for (int g = 0; g < 8; ++g) v -= bp[(size_t)(n * 8 + g) * 256 + t];
        bias_l[t] = v;
    }

    const ushort_t* msrc = M_t + (((size_t)(n * 8 + w) * 16) * 64 + l) * 8;
    short8 a[16];
    #pragma unroll
    for (int ks = 0; ks < 16; ++ks)
        a[ks] = *(const short8*)(msrc + (size_t)ks * 512);

    const ushort_t* xsrc = xbt + (size_t)(n * 512 + pt * 8) * 8192;   // 8 pb x 16KB

    #pragma unroll
    for (int p = 0; p < 2; ++p) {
        const ushort_t* src = xsrc + (size_t)p * 8192;
        gld_lds16(src + w * 1024 + l * 8,       bstage + p * 8192 + w * 1024);
        gld_lds16(src + w * 1024 + 512 + l * 8, bstage + p * 8192 + w * 1024 + 512);
    }
    asm volatile("s_waitcnt vmcnt(2) lgkmcnt(0)" ::: "memory");
    __builtin_amdgcn_s_barrier();
    __builtin_amdgcn_sched_barrier(0);

    float4 bsv4[4];
    #pragma unroll
    for (int qq = 0; qq < 4; ++qq)
        bsv4[qq] = *(const float4*)&bias_l[dblk + 8 * qq + 4 * hi];

    #pragma unroll 1
    for (int pb = 0; pb < 8; ++pb) {
        ushort_t* bufc = bstage + (pb % 3) * 8192;
        if (pb + 2 < 8) {
            ushort_t* bufn = bstage + ((pb + 2) % 3) * 8192;
            const ushort_t* src = xsrc + (size_t)(pb + 2) * 8192;
            gld_lds16(src + w * 1024 + l * 8,       bufn + w * 1024);
            gld_lds16(src + w * 1024 + 512 + l * 8, bufn + w * 1024 + 512);
        }
        __builtin_amdgcn_sched_barrier(0);

        f32x16 acc = {};
        #pragma unroll
        for (int ks = 0; ks < 16; ++ks) {
            short8 bf = *(const short8*)(bufc + ks * 512 + l * 8);
            acc = __builtin_amdgcn_mfma_f32_32x32x16_bf16(a[ks], bf, acc, 0, 0, 0);
        }

        int px = (pt * 8 + pb) * 32 + lo;
        #pragma unroll
        for (int r = 0; r < 16; ++r) {
            int row = dblk + (r & 3) + 8 * (r >> 2) + 4 * hi;
            out[((size_t)(n * 256 + row)) * HWPX + px] =
                acc[r] + ((const float*)&bsv4[r >> 2])[r & 3];
        }

        if (pb < 7) {
            asm volatile("s_waitcnt vmcnt(18)" ::: "memory");
            __builtin_amdgcn_sched_barrier(0);
            __builtin_amdgcn_s_barrier();
            __builtin_amdgcn_sched_barrier(0);
        }
    }
}

// ===================== Fallback Pass 4: fp32 x, row-major M ================
__global__ __launch_bounds__(512, 2) void k_gemm_fb(const float* __restrict__ x,
                                                    const ushort_t* __restrict__ M_bf,
                                                    const float* __restrict__ bias,
                                                    float* __restrict__ out) {
    int bid = blockIdx.x;
    int n = bid >> 8, pt = bid & 255;
    int px0 = pt * 64;
    int t = threadIdx.x, w = t >> 6, l = t & 63, lo = l & 31, hi = l >> 5;
    int dblk = w * 32;

    const ushort_t* Mrow = M_bf + ((size_t)(n * 256 + dblk + lo)) * 256;
    const float* xn = x + (size_t)n * 256 * HWPX;

    f32x16 acc0 = {}, acc1 = {};
    for (int ks = 0; ks < 16; ++ks) {
        int c0 = ks * 16 + hi * 8;
        short8 afrag = *(const short8*)(Mrow + c0);
        const float* xc = xn + (size_t)c0 * HWPX + px0 + lo;
        short8 f0, f1;
        #pragma unroll
        for (int bb = 0; bb < 8; ++bb) {
            f0[bb] = (short)f2bf(xc[(size_t)bb * HWPX]);
            f1[bb] = (short)f2bf(xc[(size_t)bb * HWPX + 32]);
        }
        acc0 = __builtin_amdgcn_mfma_f32_32x32x16_bf16(afrag, f0, acc0, 0, 0, 0);
        acc1 = __builtin_amdgcn_mfma_f32_32x32x16_bf16(afrag, f1, acc1, 0, 0, 0);
    }

    #pragma unroll
    for (int r = 0; r < 16; ++r) {
        int row = dblk + (r & 3) + 8 * (r >> 2) + 4 * hi;
        float bs = bias[n * 256 + row];
        size_t o = ((size_t)(n * 256 + row)) * HWPX + px0 + lo;
        out[o] = acc0[r] + bs;
        out[o + 32] = acc1[r] + bs;
    }
}

// ===========================================================================
extern "C" void kernel_launch(void* const* d_in, const int* in_sizes, int n_in,
                              void* d_out, int out_size, void* d_ws, size_t ws_size,
                              hipStream_t stream) {
    const float* x      = (const float*)d_in[0];
    const int*   cls    = (const int*)d_in[1];
    const float* EK     = (const float*)d_in[2];
    const float* EB     = (const float*)d_in[3];
    const float* conv_w = (const float*)d_in[4];
    const float* conv_b = (const float*)d_in[5];
    float* out = (float*)d_out;

    float* wsf   = (float*)d_ws;
    float* part  = wsf;                          // 512*1056 = 540672 f
    float* bp    = wsf + 540672;                 // 16384 f
    float* bias  = wsf + 557056;                 // 2048 f  (fallback only)
    ushort_t* M  = (ushort_t*)(wsf + 559104);    // 8*256*256 bf16 = 1 MiB

    const size_t xb_off   = 559104 * sizeof(float) + (size_t)8 * 256 * 256 * 2; // 3284992
    const size_t xb_bytes = (size_t)8 * HWPX * 256 * 2;                         // 64 MiB
    bool fast = ws_size >= xb_off + xb_bytes;
    ushort_t* xb = (ushort_t*)((char*)d_ws + xb_off);

    if (fast) {
        k_stats<true>  <<<512, 512, 0, stream>>>(x, part, xb);
        // PROBE ROUND: k_prep launched 4x on purpose (idempotent — same inputs
        // -> same M/bp stores -> deterministic). T12 - T11 = 3P isolates the
        // prep kernel's cost; the ledger (S=26 from R9 probe, G~33 from R6
        // probe) says P~38 but the barrier-chain model says P~12 — this
        // resolves which. Remove next round.
        k_prep<true>   <<<64,  256, 0, stream>>>(part, conv_w, EK, cls, M, bp);
        k_prep<true>   <<<64,  256, 0, stream>>>(part, conv_w, EK, cls, M, bp);
        k_prep<true>   <<<64,  256, 0, stream>>>(part, conv_w, EK, cls, M, bp);
        k_prep<true>   <<<64,  256, 0, stream>>>(part, conv_w, EK, cls, M, bp);
        k_gemm_s       <<<512, 512, 0, stream>>>(xb, M, conv_b, EB, cls, bp, out);
    } else {
        k_stats<false> <<<512, 512, 0, stream>>>(x, part, M);
        k_prep<false>  <<<64,  256, 0, stream>>>(part, conv_w, EK, cls, M, bp);
        k_bias         <<<8,   256, 0, stream>>>(conv_b, EB, cls, bp, bias);
        k_gemm_fb      <<<2048, 512, 0, stream>>>(x, M, bias, out);
    }
}

// Round 13
// 99.538 us; speedup vs baseline: 1.5405x; 1.5405x over previous
//
#include <hip/hip_runtime.h>

typedef unsigned short ushort_t;
typedef __attribute__((ext_vector_type(8)))  short  short8;
typedef __attribute__((ext_vector_type(8)))  ushort_t ushort8;
typedef __attribute__((ext_vector_type(16))) float  f32x16;

#define HWPX 16384
#define EPSV 0.001f

__device__ __forceinline__ ushort_t f2bf(float f) {
    unsigned u = __builtin_bit_cast(unsigned, f);
    unsigned r = u + 0x7FFFu + ((u >> 16) & 1u);   // round-to-nearest-even
    return (ushort_t)(r >> 16);
}

__device__ __forceinline__ unsigned cvt_pk(float a, float b) {
    unsigned r;
    asm("v_cvt_pk_bf16_f32 %0, %1, %2" : "=v"(r) : "v"(a), "v"(b));
    return r;   // lo = bf16(a), hi = bf16(b)
}

__device__ __forceinline__ void gld_lds16(const ushort_t* g, ushort_t* l) {
    __builtin_amdgcn_global_load_lds(
        (const __attribute__((address_space(1))) unsigned int*)g,
        (__attribute__((address_space(3))) unsigned int*)l, 16, 0, 0);
}

// ===================== Pass 1: coalesced stats + frag-ordered xb_t =========
// grid 512 = n(8) x g(8) x q(8); block 512 (8 waves). LDS 40KB. (unchanged;
// R9 probe: ~26us, ~80% of its HBM-read floor.)
__device__ __forceinline__ void stats_load(float4 (&buf)[4], const float* xbase,
                                           int w, int col4, int sub) {
    #pragma unroll
    for (int rr = 0; rr < 4; ++rr)
        buf[rr] = *(const float4*)(xbase + (size_t)(w + rr * 8) * HWPX + sub * 256 + col4 * 4);
}

template<bool XBF>
__global__ __launch_bounds__(512, 4) void k_stats(const float* __restrict__ x,
                                                  float* __restrict__ part,
                                                  ushort_t* __restrict__ xbt) {
    __shared__ char smraw[40960];         // union: tile(32KB) | redc(32KB); +redm 8KB
    ushort_t* tile = (ushort_t*)smraw;    // 2 x (32ch x 256px) bf16, swizzled
    float (*redc)[1024] = (float(*)[1024])smraw;
    float (*redm)[64] = (float(*)[64])(smraw + 32768);
    int b = blockIdx.x;
    int n = b >> 6, g = (b >> 3) & 7, q = b & 7;
    int t = threadIdx.x, w = t >> 6, l = t & 63;
    int lo = l & 31, hi = l >> 5, col4 = l;
    const float* xbase = x + ((size_t)(n * 256 + g * 32)) * HWPX + q * 2048;

    f32x16 acc = {};
    float sm[4] = {0.f, 0.f, 0.f, 0.f};
    float4 buf[4], nxt[4];

    stats_load(buf, xbase, w, col4, 0);
    #pragma unroll 1
    for (int s = 0; s < 8; ++s) {
        if (s < 7) stats_load(nxt, xbase, w, col4, s + 1);
        ushort_t* tl = tile + (s & 1) * 8192;
        #pragma unroll
        for (int rr = 0; rr < 4; ++rr) {
            float4 v = buf[rr];
            sm[rr] += v.x + v.y + v.z + v.w;
            uint2 u;
            u.x = cvt_pk(v.x, v.y);
            u.y = cvt_pk(v.z, v.w);
            int row = w + rr * 8;
            int idx = (row * 256 + col4 * 4) ^ ((row & 7) << 3);   // ushort-idx swizzle
            *(uint2*)&tl[idx] = u;
        }
        asm volatile("s_waitcnt lgkmcnt(0)" ::: "memory");
        __builtin_amdgcn_s_barrier();
        __builtin_amdgcn_sched_barrier(0);
        #pragma unroll
        for (int ks2 = 0; ks2 < 2; ++ks2) {
            int pidx = (lo * 256 + w * 32 + ks2 * 16 + hi * 8) ^ ((lo & 7) << 3);
            short8 f = *(const short8*)&tl[pidx];
            acc = __builtin_amdgcn_mfma_f32_32x32x16_bf16(f, f, acc, 0, 0, 0);
        }
        if (XBF) {
            int pb = q * 64 + s * 8 + w;
            #pragma unroll
            for (int h = 0; h < 2; ++h) {
                ushort8 o;
                #pragma unroll
                for (int j = 0; j < 8; ++j) {
                    int c = h * 16 + hi * 8 + j;
                    o[j] = tl[(c * 256 + w * 32 + lo) ^ ((c & 7) << 3)];
                }
                *(ushort8*)(xbt + ((((size_t)(n * 512 + pb)) * 16 + g * 2 + h) * 64 + l) * 8) = o;
            }
        }
        #pragma unroll
        for (int rr = 0; rr < 4; ++rr) buf[rr] = nxt[rr];
    }

    __syncthreads();
    #pragma unroll
    for (int r = 0; r < 16; ++r) redc[w][l * 16 + r] = acc[r];
    #pragma unroll
    for (int rr = 0; rr < 4; ++rr) redm[w + rr * 8][col4] = sm[rr];
    __syncthreads();

    for (int i = t; i < 1024; i += 512) {
        float v = 0.f;
        #pragma unroll
        for (int ww = 0; ww < 8; ++ww) v += redc[ww][i];
        int ll = i >> 4, r = i & 15;
        int row = (r & 3) + 8 * (r >> 2) + 4 * (ll >> 5);   // C/D layout 32x32 (m74/m101)
        int col = ll & 31;
        part[(size_t)b * 1056 + row * 32 + col] = v;
    }
    if (t < 32) {
        float v = 0.f;
        for (int c = 0; c < 64; ++c) v += redm[t][c];
        part[(size_t)b * 1056 + 1024 + t] = v;
    }
}

// ===================== Pass 2: reduce + rank-2 LDS chol + compose ==========
// grid 64 = n*8+g; block 256.  Changes vs R11 (math-identical):
//  - a[] gather (EK + staged conv_w) HOISTED before the chol chain so the
//    HBM loads hide under the barrier latencies.
//  - rank-2 pivot phases: phase k (even) applies pivots k,k+1 to cols j>k+1,
//    computing the intermediate col-(k+1) values redundantly in registers
//    (reads only -> race-free). Odd columns stay stale in LDS; the normalize
//    pass applies their final pivot-(j-1) rank-1 analytically. 33 -> 17
//    barriers. (R12 probe: P=17.1us, dominated by the barrier latency chain.)
template<bool FRAG>
__global__ __launch_bounds__(256, 1) void k_prep(const float* __restrict__ part,
                                                 const float* __restrict__ conv_w,
                                                 const float* __restrict__ EK,
                                                 const int* __restrict__ cls_arr,
                                                 ushort_t* __restrict__ M_bf,
                                                 float* __restrict__ bp) {
    int bid = blockIdx.x;
    int n = bid >> 3, g = bid & 7;
    int t = threadIdx.x;
    __shared__ float cov[1024];
    __shared__ float sums[32];
    __shared__ float A[32][33];     // cov' -> L (lower; odd cols finalized in normalize)
    __shared__ float ml[32];
    __shared__ float cw[256][33];   // conv_w slice, padded

    for (int i = 0; i < 8; ++i) {
        int r = i * 32 + (t >> 3);
        float4 v = *(const float4*)(conv_w + r * 256 + g * 32 + (t & 7) * 4);
        #pragma unroll
        for (int e = 0; e < 4; ++e) cw[r][(t & 7) * 4 + e] = ((float*)&v)[e];
    }

    for (int i = t; i < 1024; i += 256) {
        float v = 0.f;
        for (int q = 0; q < 8; ++q) v += part[(size_t)(bid * 8 + q) * 1056 + i];
        cov[i] = v;
    }
    if (t < 32) {
        float v = 0.f;
        for (int q = 0; q < 8; ++q) v += part[(size_t)(bid * 8 + q) * 1056 + 1024 + t];
        sums[t] = v;
    }
    __syncthreads();

    const float invHW = 1.0f / (float)HWPX;
    #pragma unroll
    for (int p = 0; p < 4; ++p) {
        int idx = t + p * 256;
        int r = idx >> 5, c = idx & 31;
        float mr = sums[r] * invHW, mc = sums[c] * invHW;
        A[r][c] = (cov[idx] * invHW - mr * mc) * (1.0f - EPSV) + ((r == c) ? EPSV : 0.f);
    }
    if (t < 32) ml[t] = sums[t] * invHW;
    __syncthreads();

    // hoisted gather: independent of chol; loads retire under the barrier chain
    int d = t;
    int cls = cls_arr[n];
    float a[32];
    #pragma unroll
    for (int c = 0; c < 32; ++c)
        a[c] = cw[d][c] + EK[(size_t)cls * 65536 + (size_t)(g * 32 + c) * 256 + d];

    // --- rank-2 cholesky phases (15 barriers) ---
    for (int k = 0; k < 30; k += 2) {
        float d0 = A[k][k];
        float invd0 = 1.0f / d0;
        float r10 = A[k + 1][k] * invd0;
        float d1 = A[k + 1][k + 1] - A[k + 1][k] * r10;
        float invd1 = 1.0f / d1;
        #pragma unroll
        for (int p = 0; p < 4; ++p) {
            int idx = t + p * 256;
            int i = idx >> 5, j = idx & 31;
            if (j > k + 1 && j <= i) {
                float aik = A[i][k], ajk = A[j][k];
                float ai1 = A[i][k + 1] - aik * r10;
                float aj1 = A[j][k + 1] - ajk * r10;
                A[i][j] = A[i][j] - aik * ajk * invd0 - ai1 * aj1 * invd1;
            }
        }
        __syncthreads();
    }
    // --- normalize (+ final pivot for odd columns), 2 barriers ---
    {
        float vals[4], dsq[4];
        #pragma unroll
        for (int p = 0; p < 4; ++p) {
            int idx = t + p * 256;
            int i = idx >> 5, j = idx & 31;
            float v, dj;
            if (j & 1) {
                float r = A[j][j - 1] / A[j - 1][j - 1];
                dj = A[j][j] - A[j][j - 1] * r;       // = trailing diag after pivot j-1
                v  = A[i][j] - A[i][j - 1] * r;       // apply pivot j-1 rank-1
            } else {
                dj = A[j][j];
                v  = A[i][j];
            }
            vals[p] = v;
            dsq[p] = sqrtf(dj);
        }
        __syncthreads();
        #pragma unroll
        for (int p = 0; p < 4; ++p) {
            int idx = t + p * 256;
            int i = idx >> 5, j = idx & 31;
            if (j <= i) A[i][j] = vals[p] / dsq[p];
        }
        __syncthreads();
    }

    // --- compose: thread = output row d; solve m·L = a (back-substitution) ---
    float m[32];
    #pragma unroll
    for (int j = 31; j >= 0; --j) {
        float s = a[j];
        #pragma unroll
        for (int cp = j + 1; cp < 32; ++cp) s -= m[cp] * A[cp][j];   // broadcast reads
        m[j] = s / A[j][j];
    }

    float bpv = 0.f;
    ushort8 pk[4];
    #pragma unroll
    for (int cp = 0; cp < 32; ++cp) {
        bpv += m[cp] * ml[cp];
        pk[cp >> 3][cp & 7] = f2bf(m[cp]);
    }
    if (FRAG) {
        #pragma unroll
        for (int kk = 0; kk < 4; ++kk) {
            size_t u = (((size_t)(n * 8 + (d >> 5)) * 16) + g * 2 + (kk >> 1)) * 64
                       + (d & 31) + 32 * (kk & 1);
            *(ushort8*)(M_bf + u * 8) = pk[kk];
        }
    } else {
        ushort_t* dst = M_bf + ((size_t)(n * 256 + d)) * 256 + g * 32;
        #pragma unroll
        for (int k = 0; k < 4; ++k) *(ushort8*)(dst + k * 8) = pk[k];
    }
    bp[(size_t)(n * 8 + g) * 256 + d] = bpv;
}

// ===================== Pass 3 (fallback only): bias ========================
__global__ __launch_bounds__(256) void k_bias(const float* __restrict__ conv_b,
                                              const float* __restrict__ EB,
                                              const int* __restrict__ cls_arr,
                                              const float* __restrict__ bp,
                                              float* __restrict__ bias) {
    int n = blockIdx.x, d = threadIdx.x;
    int cls = cls_arr[n];
    float v = conv_b[d] + EB[cls * 256 + d];
    #pragma unroll
    for (int g = 0; g < 8; ++g) v -= bp[(size_t)(n * 8 + g) * 256 + d];
    bias[n * 256 + d] = v;
}

// ===================== Pass 4: out = M_t * xb_t + bias =====================
// Change vs R11: counted vmcnt per iteration {pb0:18, pb1-5:34, pb6:32} so the
// PREVIOUS iteration's 16 output stores stay in flight across the barrier
// (correctness only needs gld(pb+1) retired; vmcnt retires in-order, m135).
// R11's vmcnt(18) forced a full HBM write-drain every iteration.
__global__ __launch_bounds__(512, 4) void k_gemm_s(const ushort_t* __restrict__ xbt,
                                                   const ushort_t* __restrict__ M_t,
                                                   const float* __restrict__ conv_b,
                                                   const float* __restrict__ EB,
                                                   const int* __restrict__ cls_arr,
                                                   const float* __restrict__ bp,
                                                   float* __restrict__ out) {
    __shared__ ushort_t bstage[24576];   // 3 x 16KB
    __shared__ float bias_l[256];
    int bid = blockIdx.x;
    int n = bid >> 6, pt = bid & 63;
    int t = threadIdx.x, w = t >> 6, l = t & 63, lo = l & 31, hi = l >> 5;
    int dblk = w * 32;

    if (t < 256) {
        int cls = cls_arr[n];
        float v = conv_b[t] + EB[cls * 256 + t];
        #pragma unroll
        for (int g = 0; g < 8; ++g) v -= bp[(size_t)(n * 8 + g) * 256 + t];
        bias_l[t] = v;
    }

    const ushort_t* msrc = M_t + (((size_t)(n * 8 + w) * 16) * 64 + l) * 8;
    short8 a[16];
    #pragma unroll
    for (int ks = 0; ks < 16; ++ks)
        a[ks] = *(const short8*)(msrc + (size_t)ks * 512);

    const ushort_t* xsrc = xbt + (size_t)(n * 512 + pt * 8) * 8192;   // 8 pb x 16KB

    #pragma unroll
    for (int p = 0; p < 2; ++p) {
        const ushort_t* src = xsrc + (size_t)p * 8192;
        gld_lds16(src + w * 1024 + l * 8,       bstage + p * 8192 + w * 1024);
        gld_lds16(src + w * 1024 + 512 + l * 8, bstage + p * 8192 + w * 1024 + 512);
    }
    asm volatile("s_waitcnt vmcnt(2) lgkmcnt(0)" ::: "memory");  // gld(0) + bias_l done
    __builtin_amdgcn_s_barrier();
    __builtin_amdgcn_sched_barrier(0);

    float4 bsv4[4];
    #pragma unroll
    for (int qq = 0; qq < 4; ++qq)
        bsv4[qq] = *(const float4*)&bias_l[dblk + 8 * qq + 4 * hi];

    #pragma unroll 1
    for (int pb = 0; pb < 8; ++pb) {
        ushort_t* bufc = bstage + (pb % 3) * 8192;
        if (pb + 2 < 8) {
            ushort_t* bufn = bstage + ((pb + 2) % 3) * 8192;
            const ushort_t* src = xsrc + (size_t)(pb + 2) * 8192;
            gld_lds16(src + w * 1024 + l * 8,       bufn + w * 1024);
            gld_lds16(src + w * 1024 + 512 + l * 8, bufn + w * 1024 + 512);
        }
        __builtin_amdgcn_sched_barrier(0);

        f32x16 acc = {};
        #pragma unroll
        for (int ks = 0; ks < 16; ++ks) {
            short8 bf = *(const short8*)(bufc + ks * 512 + l * 8);
            acc = __builtin_amdgcn_mfma_f32_32x32x16_bf16(a[ks], bf, acc, 0, 0, 0);
        }

        int px = (pt * 8 + pb) * 32 + lo;
        #pragma unroll
        for (int r = 0; r < 16; ++r) {
            int row = dblk + (r & 3) + 8 * (r >> 2) + 4 * hi;
            out[((size_t)(n * 256 + row)) * HWPX + px] =
                acc[r] + ((const float*)&bsv4[r >> 2])[r & 3];
        }

        if (pb < 7) {
            // Wait exactly until gld(pb+1) retired; prior stores may stay in
            // flight. In-order retirement counts (newest-first at this point):
            //  pb=0:  16 st(0) + 2 gld(2)                     -> vmcnt(18)
            //  pb1-5: 16 st(pb) + 2 gld(pb+2) + 16 st(pb-1)   -> vmcnt(34)
            //  pb=6:  16 st(6) + 16 st(5)                     -> vmcnt(32)
            if (pb == 0)     asm volatile("s_waitcnt vmcnt(18)" ::: "memory");
            else if (pb < 6) asm volatile("s_waitcnt vmcnt(34)" ::: "memory");
            else             asm volatile("s_waitcnt vmcnt(32)" ::: "memory");
            __builtin_amdgcn_sched_barrier(0);
            __builtin_amdgcn_s_barrier();
            __builtin_amdgcn_sched_barrier(0);
        }
    }
}

// ===================== Fallback Pass 4: fp32 x, row-major M ================
__global__ __launch_bounds__(512, 2) void k_gemm_fb(const float* __restrict__ x,
                                                    const ushort_t* __restrict__ M_bf,
                                                    const float* __restrict__ bias,
                                                    float* __restrict__ out) {
    int bid = blockIdx.x;
    int n = bid >> 8, pt = bid & 255;
    int px0 = pt * 64;
    int t = threadIdx.x, w = t >> 6, l = t & 63, lo = l & 31, hi = l >> 5;
    int dblk = w * 32;

    const ushort_t* Mrow = M_bf + ((size_t)(n * 256 + dblk + lo)) * 256;
    const float* xn = x + (size_t)n * 256 * HWPX;

    f32x16 acc0 = {}, acc1 = {};
    for (int ks = 0; ks < 16; ++ks) {
        int c0 = ks * 16 + hi * 8;
        short8 afrag = *(const short8*)(Mrow + c0);
        const float* xc = xn + (size_t)c0 * HWPX + px0 + lo;
        short8 f0, f1;
        #pragma unroll
        for (int bb = 0; bb < 8; ++bb) {
            f0[bb] = (short)f2bf(xc[(size_t)bb * HWPX]);
            f1[bb] = (short)f2bf(xc[(size_t)bb * HWPX + 32]);
        }
        acc0 = __builtin_amdgcn_mfma_f32_32x32x16_bf16(afrag, f0, acc0, 0, 0, 0);
        acc1 = __builtin_amdgcn_mfma_f32_32x32x16_bf16(afrag, f1, acc1, 0, 0, 0);
    }

    #pragma unroll
    for (int r = 0; r < 16; ++r) {
        int row = dblk + (r & 3) + 8 * (r >> 2) + 4 * hi;
        float bs = bias[n * 256 + row];
        size_t o = ((size_t)(n * 256 + row)) * HWPX + px0 + lo;
        out[o] = acc0[r] + bs;
        out[o + 32] = acc1[r] + bs;
    }
}

// ===========================================================================
extern "C" void kernel_launch(void* const* d_in, const int* in_sizes, int n_in,
                              void* d_out, int out_size, void* d_ws, size_t ws_size,
                              hipStream_t stream) {
    const float* x      = (const float*)d_in[0];
    const int*   cls    = (const int*)d_in[1];
    const float* EK     = (const float*)d_in[2];
    const float* EB     = (const float*)d_in[3];
    const float* conv_w = (const float*)d_in[4];
    const float* conv_b = (const float*)d_in[5];
    float* out = (float*)d_out;

    float* wsf   = (float*)d_ws;
    float* part  = wsf;                          // 512*1056 = 540672 f
    float* bp    = wsf + 540672;                 // 16384 f
    float* bias  = wsf + 557056;                 // 2048 f  (fallback only)
    ushort_t* M  = (ushort_t*)(wsf + 559104);    // 8*256*256 bf16 = 1 MiB

    const size_t xb_off   = 559104 * sizeof(float) + (size_t)8 * 256 * 256 * 2; // 3284992
    const size_t xb_bytes = (size_t)8 * HWPX * 256 * 2;                         // 64 MiB
    bool fast = ws_size >= xb_off + xb_bytes;
    ushort_t* xb = (ushort_t*)((char*)d_ws + xb_off);

    if (fast) {
        k_stats<true>  <<<512, 512, 0, stream>>>(x, part, xb);
        k_prep<true>   <<<64,  256, 0, stream>>>(part, conv_w, EK, cls, M, bp);
        k_gemm_s       <<<512, 512, 0, stream>>>(xb, M, conv_b, EB, cls, bp, out);
    } else {
        k_stats<false> <<<512, 512, 0, stream>>>(x, part, M);
        k_prep<false>  <<<64,  256, 0, stream>>>(part, conv_w, EK, cls, M, bp);
        k_bias         <<<8,   256, 0, stream>>>(conv_b, EB, cls, bp, bias);
        k_gemm_fb      <<<2048, 512, 0, stream>>>(x, M, bias, out);
    }
}

// Round 14
// 99.217 us; speedup vs baseline: 1.5455x; 1.0032x over previous
//
#include <hip/hip_runtime.h>

typedef unsigned short ushort_t;
typedef __attribute__((ext_vector_type(8)))  short  short8;
typedef __attribute__((ext_vector_type(8)))  ushort_t ushort8;
typedef __attribute__((ext_vector_type(16))) float  f32x16;

#define HWPX 16384
#define EPSV 0.001f

__device__ __forceinline__ ushort_t f2bf(float f) {
    unsigned u = __builtin_bit_cast(unsigned, f);
    unsigned r = u + 0x7FFFu + ((u >> 16) & 1u);   // round-to-nearest-even
    return (ushort_t)(r >> 16);
}

__device__ __forceinline__ unsigned cvt_pk(float a, float b) {
    unsigned r;
    asm("v_cvt_pk_bf16_f32 %0, %1, %2" : "=v"(r) : "v"(a), "v"(b));
    return r;   // lo = bf16(a), hi = bf16(b)
}

__device__ __forceinline__ void gld_lds16(const ushort_t* g, ushort_t* l) {
    __builtin_amdgcn_global_load_lds(
        (const __attribute__((address_space(1))) unsigned int*)g,
        (__attribute__((address_space(3))) unsigned int*)l, 16, 0, 0);
}

// ===================== Pass 1: coalesced stats + frag-ordered xb_t =========
// grid 512 = n(8) x g(8) x q(8); block 512 (8 waves). LDS 40KB. (unchanged;
// R9 probe: ~26us warm / ~31us cold = at its read+write HBM floor.)
__device__ __forceinline__ void stats_load(float4 (&buf)[4], const float* xbase,
                                           int w, int col4, int sub) {
    #pragma unroll
    for (int rr = 0; rr < 4; ++rr)
        buf[rr] = *(const float4*)(xbase + (size_t)(w + rr * 8) * HWPX + sub * 256 + col4 * 4);
}

template<bool XBF>
__global__ __launch_bounds__(512, 4) void k_stats(const float* __restrict__ x,
                                                  float* __restrict__ part,
                                                  ushort_t* __restrict__ xbt) {
    __shared__ char smraw[40960];         // union: tile(32KB) | redc(32KB); +redm 8KB
    ushort_t* tile = (ushort_t*)smraw;    // 2 x (32ch x 256px) bf16, swizzled
    float (*redc)[1024] = (float(*)[1024])smraw;
    float (*redm)[64] = (float(*)[64])(smraw + 32768);
    int b = blockIdx.x;
    int n = b >> 6, g = (b >> 3) & 7, q = b & 7;
    int t = threadIdx.x, w = t >> 6, l = t & 63;
    int lo = l & 31, hi = l >> 5, col4 = l;
    const float* xbase = x + ((size_t)(n * 256 + g * 32)) * HWPX + q * 2048;

    f32x16 acc = {};
    float sm[4] = {0.f, 0.f, 0.f, 0.f};
    float4 buf[4], nxt[4];

    stats_load(buf, xbase, w, col4, 0);
    #pragma unroll 1
    for (int s = 0; s < 8; ++s) {
        if (s < 7) stats_load(nxt, xbase, w, col4, s + 1);
        ushort_t* tl = tile + (s & 1) * 8192;
        #pragma unroll
        for (int rr = 0; rr < 4; ++rr) {
            float4 v = buf[rr];
            sm[rr] += v.x + v.y + v.z + v.w;
            uint2 u;
            u.x = cvt_pk(v.x, v.y);
            u.y = cvt_pk(v.z, v.w);
            int row = w + rr * 8;
            int idx = (row * 256 + col4 * 4) ^ ((row & 7) << 3);   // ushort-idx swizzle
            *(uint2*)&tl[idx] = u;
        }
        asm volatile("s_waitcnt lgkmcnt(0)" ::: "memory");
        __builtin_amdgcn_s_barrier();
        __builtin_amdgcn_sched_barrier(0);
        #pragma unroll
        for (int ks2 = 0; ks2 < 2; ++ks2) {
            int pidx = (lo * 256 + w * 32 + ks2 * 16 + hi * 8) ^ ((lo & 7) << 3);
            short8 f = *(const short8*)&tl[pidx];
            acc = __builtin_amdgcn_mfma_f32_32x32x16_bf16(f, f, acc, 0, 0, 0);
        }
        if (XBF) {
            int pb = q * 64 + s * 8 + w;
            #pragma unroll
            for (int h = 0; h < 2; ++h) {
                ushort8 o;
                #pragma unroll
                for (int j = 0; j < 8; ++j) {
                    int c = h * 16 + hi * 8 + j;
                    o[j] = tl[(c * 256 + w * 32 + lo) ^ ((c & 7) << 3)];
                }
                *(ushort8*)(xbt + ((((size_t)(n * 512 + pb)) * 16 + g * 2 + h) * 64 + l) * 8) = o;
            }
        }
        #pragma unroll
        for (int rr = 0; rr < 4; ++rr) buf[rr] = nxt[rr];
    }

    __syncthreads();
    #pragma unroll
    for (int r = 0; r < 16; ++r) redc[w][l * 16 + r] = acc[r];
    #pragma unroll
    for (int rr = 0; rr < 4; ++rr) redm[w + rr * 8][col4] = sm[rr];
    __syncthreads();

    for (int i = t; i < 1024; i += 512) {
        float v = 0.f;
        #pragma unroll
        for (int ww = 0; ww < 8; ++ww) v += redc[ww][i];
        int ll = i >> 4, r = i & 15;
        int row = (r & 3) + 8 * (r >> 2) + 4 * (ll >> 5);   // C/D layout 32x32 (m74/m101)
        int col = ll & 31;
        part[(size_t)b * 1056 + row * 32 + col] = v;
    }
    if (t < 32) {
        float v = 0.f;
        for (int c = 0; c < 64; ++c) v += redm[t][c];
        part[(size_t)b * 1056 + 1024 + t] = v;
    }
}

// ===================== Pass 2: reduce + rank-2 LDS chol + compose ==========
// (unchanged R13)
template<bool FRAG>
__global__ __launch_bounds__(256, 1) void k_prep(const float* __restrict__ part,
                                                 const float* __restrict__ conv_w,
                                                 const float* __restrict__ EK,
                                                 const int* __restrict__ cls_arr,
                                                 ushort_t* __restrict__ M_bf,
                                                 float* __restrict__ bp) {
    int bid = blockIdx.x;
    int n = bid >> 3, g = bid & 7;
    int t = threadIdx.x;
    __shared__ float cov[1024];
    __shared__ float sums[32];
    __shared__ float A[32][33];     // cov' -> L (lower; odd cols finalized in normalize)
    __shared__ float ml[32];
    __shared__ float cw[256][33];   // conv_w slice, padded

    for (int i = 0; i < 8; ++i) {
        int r = i * 32 + (t >> 3);
        float4 v = *(const float4*)(conv_w + r * 256 + g * 32 + (t & 7) * 4);
        #pragma unroll
        for (int e = 0; e < 4; ++e) cw[r][(t & 7) * 4 + e] = ((float*)&v)[e];
    }

    for (int i = t; i < 1024; i += 256) {
        float v = 0.f;
        for (int q = 0; q < 8; ++q) v += part[(size_t)(bid * 8 + q) * 1056 + i];
        cov[i] = v;
    }
    if (t < 32) {
        float v = 0.f;
        for (int q = 0; q < 8; ++q) v += part[(size_t)(bid * 8 + q) * 1056 + 1024 + t];
        sums[t] = v;
    }
    __syncthreads();

    const float invHW = 1.0f / (float)HWPX;
    #pragma unroll
    for (int p = 0; p < 4; ++p) {
        int idx = t + p * 256;
        int r = idx >> 5, c = idx & 31;
        float mr = sums[r] * invHW, mc = sums[c] * invHW;
        A[r][c] = (cov[idx] * invHW - mr * mc) * (1.0f - EPSV) + ((r == c) ? EPSV : 0.f);
    }
    if (t < 32) ml[t] = sums[t] * invHW;
    __syncthreads();

    // hoisted gather: independent of chol; loads retire under the barrier chain
    int d = t;
    int cls = cls_arr[n];
    float a[32];
    #pragma unroll
    for (int c = 0; c < 32; ++c)
        a[c] = cw[d][c] + EK[(size_t)cls * 65536 + (size_t)(g * 32 + c) * 256 + d];

    // --- rank-2 cholesky phases (15 barriers) ---
    for (int k = 0; k < 30; k += 2) {
        float d0 = A[k][k];
        float invd0 = 1.0f / d0;
        float r10 = A[k + 1][k] * invd0;
        float d1 = A[k + 1][k + 1] - A[k + 1][k] * r10;
        float invd1 = 1.0f / d1;
        #pragma unroll
        for (int p = 0; p < 4; ++p) {
            int idx = t + p * 256;
            int i = idx >> 5, j = idx & 31;
            if (j > k + 1 && j <= i) {
                float aik = A[i][k], ajk = A[j][k];
                float ai1 = A[i][k + 1] - aik * r10;
                float aj1 = A[j][k + 1] - ajk * r10;
                A[i][j] = A[i][j] - aik * ajk * invd0 - ai1 * aj1 * invd1;
            }
        }
        __syncthreads();
    }
    // --- normalize (+ final pivot for odd columns), 2 barriers ---
    {
        float vals[4], dsq[4];
        #pragma unroll
        for (int p = 0; p < 4; ++p) {
            int idx = t + p * 256;
            int i = idx >> 5, j = idx & 31;
            float v, dj;
            if (j & 1) {
                float r = A[j][j - 1] / A[j - 1][j - 1];
                dj = A[j][j] - A[j][j - 1] * r;       // = trailing diag after pivot j-1
                v  = A[i][j] - A[i][j - 1] * r;       // apply pivot j-1 rank-1
            } else {
                dj = A[j][j];
                v  = A[i][j];
            }
            vals[p] = v;
            dsq[p] = sqrtf(dj);
        }
        __syncthreads();
        #pragma unroll
        for (int p = 0; p < 4; ++p) {
            int idx = t + p * 256;
            int i = idx >> 5, j = idx & 31;
            if (j <= i) A[i][j] = vals[p] / dsq[p];
        }
        __syncthreads();
    }

    // --- compose: thread = output row d; solve m·L = a (back-substitution) ---
    float m[32];
    #pragma unroll
    for (int j = 31; j >= 0; --j) {
        float s = a[j];
        #pragma unroll
        for (int cp = j + 1; cp < 32; ++cp) s -= m[cp] * A[cp][j];   // broadcast reads
        m[j] = s / A[j][j];
    }

    float bpv = 0.f;
    ushort8 pk[4];
    #pragma unroll
    for (int cp = 0; cp < 32; ++cp) {
        bpv += m[cp] * ml[cp];
        pk[cp >> 3][cp & 7] = f2bf(m[cp]);
    }
    if (FRAG) {
        #pragma unroll
        for (int kk = 0; kk < 4; ++kk) {
            size_t u = (((size_t)(n * 8 + (d >> 5)) * 16) + g * 2 + (kk >> 1)) * 64
                       + (d & 31) + 32 * (kk & 1);
            *(ushort8*)(M_bf + u * 8) = pk[kk];
        }
    } else {
        ushort_t* dst = M_bf + ((size_t)(n * 256 + d)) * 256 + g * 32;
        #pragma unroll
        for (int k = 0; k < 4; ++k) *(ushort8*)(dst + k * 8) = pk[k];
    }
    bp[(size_t)(n * 8 + g) * 256 + d] = bpv;
}

// ===================== Pass 3 (fallback only): bias ========================
__global__ __launch_bounds__(256) void k_bias(const float* __restrict__ conv_b,
                                              const float* __restrict__ EB,
                                              const int* __restrict__ cls_arr,
                                              const float* __restrict__ bp,
                                              float* __restrict__ bias) {
    int n = blockIdx.x, d = threadIdx.x;
    int cls = cls_arr[n];
    float v = conv_b[d] + EB[cls * 256 + d];
    #pragma unroll
    for (int g = 0; g < 8; ++g) v -= bp[(size_t)(n * 8 + g) * 256 + d];
    bias[n * 256 + d] = v;
}

// ===================== Pass 4: out = M_t * xb_t + bias =====================
// Change vs R13: 4-deep LDS pipeline (4 x 16KB buffers, prefetch issued 3
// steps ahead -> ~1500cyc lead, covers HBM-miss latency; was 1.5 steps).
// Counted in-order vmcnt per step W[pb]={20,36,52,52,52,50,48}: gld(pb+1)
// retired, up to 3 steps of output stores stay in flight across the barrier.
// LDS 65KB/block -> still exactly 2 blocks/CU.
__global__ __launch_bounds__(512, 4) void k_gemm_s(const ushort_t* __restrict__ xbt,
                                                   const ushort_t* __restrict__ M_t,
                                                   const float* __restrict__ conv_b,
                                                   const float* __restrict__ EB,
                                                   const int* __restrict__ cls_arr,
                                                   const float* __restrict__ bp,
                                                   float* __restrict__ out) {
    __shared__ ushort_t bstage[32768];   // 4 x 16KB
    __shared__ float bias_l[256];
    int bid = blockIdx.x;
    int n = bid >> 6, pt = bid & 63;
    int t = threadIdx.x, w = t >> 6, l = t & 63, lo = l & 31, hi = l >> 5;
    int dblk = w * 32;

    if (t < 256) {
        int cls = cls_arr[n];
        float v = conv_b[t] + EB[cls * 256 + t];
        #pragma unroll
        for (int g = 0; g < 8; ++g) v -= bp[(size_t)(n * 8 + g) * 256 + t];
        bias_l[t] = v;
    }

    const ushort_t* msrc = M_t + (((size_t)(n * 8 + w) * 16) * 64 + l) * 8;
    short8 a[16];
    #pragma unroll
    for (int ks = 0; ks < 16; ++ks)
        a[ks] = *(const short8*)(msrc + (size_t)ks * 512);

    const ushort_t* xsrc = xbt + (size_t)(n * 512 + pt * 8) * 8192;   // 8 pb x 16KB

    // prologue: stage pb=0,1,2
    #pragma unroll
    for (int p = 0; p < 3; ++p) {
        const ushort_t* src = xsrc + (size_t)p * 8192;
        gld_lds16(src + w * 1024 + l * 8,       bstage + p * 8192 + w * 1024);
        gld_lds16(src + w * 1024 + 512 + l * 8, bstage + p * 8192 + w * 1024 + 512);
    }
    asm volatile("s_waitcnt vmcnt(4) lgkmcnt(0)" ::: "memory");  // gld(0) + bias_l done
    __builtin_amdgcn_s_barrier();
    __builtin_amdgcn_sched_barrier(0);

    float4 bsv4[4];
    #pragma unroll
    for (int qq = 0; qq < 4; ++qq)
        bsv4[qq] = *(const float4*)&bias_l[dblk + 8 * qq + 4 * hi];

    #pragma unroll 1
    for (int pb = 0; pb < 8; ++pb) {
        ushort_t* bufc = bstage + (pb & 3) * 8192;
        if (pb + 3 < 8) {
            ushort_t* bufn = bstage + ((pb + 3) & 3) * 8192;   // holds pb-1 (consumed)
            const ushort_t* src = xsrc + (size_t)(pb + 3) * 8192;
            gld_lds16(src + w * 1024 + l * 8,       bufn + w * 1024);
            gld_lds16(src + w * 1024 + 512 + l * 8, bufn + w * 1024 + 512);
        }
        __builtin_amdgcn_sched_barrier(0);

        f32x16 acc = {};
        #pragma unroll
        for (int ks = 0; ks < 16; ++ks) {
            short8 bf = *(const short8*)(bufc + ks * 512 + l * 8);
            acc = __builtin_amdgcn_mfma_f32_32x32x16_bf16(a[ks], bf, acc, 0, 0, 0);
        }

        int px = (pt * 8 + pb) * 32 + lo;
        #pragma unroll
        for (int r = 0; r < 16; ++r) {
            int row = dblk + (r & 3) + 8 * (r >> 2) + 4 * hi;
            out[((size_t)(n * 256 + row)) * HWPX + px] =
                acc[r] + ((const float*)&bsv4[r >> 2])[r & 3];
        }

        if (pb < 7) {
            // Wait exactly until gld(pb+1) retired (in-order retirement).
            // Ops issued after gld(pb+1) at this point:
            //  pb=0: 16 st(0) + gld(2),gld(3)                    -> 20
            //  pb=1: 32 st(0,1) + gld(3),gld(4)                  -> 36
            //  pb=2..4: 48 st(pb-2..pb) + 2 glds + 2 glds        -> 52
            //  pb=5: 48 st + gld(7)                              -> 50
            //  pb=6: 48 st                                       -> 48
            if (pb == 0)      asm volatile("s_waitcnt vmcnt(20)" ::: "memory");
            else if (pb == 1) asm volatile("s_waitcnt vmcnt(36)" ::: "memory");
            else if (pb < 5)  asm volatile("s_waitcnt vmcnt(52)" ::: "memory");
            else if (pb == 5) asm volatile("s_waitcnt vmcnt(50)" ::: "memory");
            else              asm volatile("s_waitcnt vmcnt(48)" ::: "memory");
            __builtin_amdgcn_sched_barrier(0);
            __builtin_amdgcn_s_barrier();
            __builtin_amdgcn_sched_barrier(0);
        }
    }
}

// ===================== Fallback Pass 4: fp32 x, row-major M ================
__global__ __launch_bounds__(512, 2) void k_gemm_fb(const float* __restrict__ x,
                                                    const ushort_t* __restrict__ M_bf,
                                                    const float* __restrict__ bias,
                                                    float* __restrict__ out) {
    int bid = blockIdx.x;
    int n = bid >> 8, pt = bid & 255;
    int px0 = pt * 64;
    int t = threadIdx.x, w = t >> 6, l = t & 63, lo = l & 31, hi = l >> 5;
    int dblk = w * 32;

    const ushort_t* Mrow = M_bf + ((size_t)(n * 256 + dblk + lo)) * 256;
    const float* xn = x + (size_t)n * 256 * HWPX;

    f32x16 acc0 = {}, acc1 = {};
    for (int ks = 0; ks < 16; ++ks) {
        int c0 = ks * 16 + hi * 8;
        short8 afrag = *(const short8*)(Mrow + c0);
        const float* xc = xn + (size_t)c0 * HWPX + px0 + lo;
        short8 f0, f1;
        #pragma unroll
        for (int bb = 0; bb < 8; ++bb) {
            f0[bb] = (short)f2bf(xc[(size_t)bb * HWPX]);
            f1[bb] = (short)f2bf(xc[(size_t)bb * HWPX + 32]);
        }
        acc0 = __builtin_amdgcn_mfma_f32_32x32x16_bf16(afrag, f0, acc0, 0, 0, 0);
        acc1 = __builtin_amdgcn_mfma_f32_32x32x16_bf16(afrag, f1, acc1, 0, 0, 0);
    }

    #pragma unroll
    for (int r = 0; r < 16; ++r) {
        int row = dblk + (r & 3) + 8 * (r >> 2) + 4 * hi;
        float bs = bias[n * 256 + row];
        size_t o = ((size_t)(n * 256 + row)) * HWPX + px0 + lo;
        out[o] = acc0[r] + bs;
        out[o + 32] = acc1[r] + bs;
    }
}

// ===========================================================================
extern "C" void kernel_launch(void* const* d_in, const int* in_sizes, int n_in,
                              void* d_out, int out_size, void* d_ws, size_t ws_size,
                              hipStream_t stream) {
    const float* x      = (const float*)d_in[0];
    const int*   cls    = (const int*)d_in[1];
    const float* EK     = (const float*)d_in[2];
    const float* EB     = (const float*)d_in[3];
    const float* conv_w = (const float*)d_in[4];
    const float* conv_b = (const float*)d_in[5];
    float* out = (float*)d_out;

    float* wsf   = (float*)d_ws;
    float* part  = wsf;                          // 512*1056 = 540672 f
    float* bp    = wsf + 540672;                 // 16384 f
    float* bias  = wsf + 557056;                 // 2048 f  (fallback only)
    ushort_t* M  = (ushort_t*)(wsf + 559104);    // 8*256*256 bf16 = 1 MiB

    const size_t xb_off   = 559104 * sizeof(float) + (size_t)8 * 256 * 256 * 2; // 3284992
    const size_t xb_bytes = (size_t)8 * HWPX * 256 * 2;                         // 64 MiB
    bool fast = ws_size >= xb_off + xb_bytes;
    ushort_t* xb = (ushort_t*)((char*)d_ws + xb_off);

    if (fast) {
        k_stats<true>  <<<512, 512, 0, stream>>>(x, part, xb);
        k_prep<true>   <<<64,  256, 0, stream>>>(part, conv_w, EK, cls, M, bp);
        k_gemm_s       <<<512, 512, 0, stream>>>(xb, M, conv_b, EB, cls, bp, out);
    } else {
        k_stats<false> <<<512, 512, 0, stream>>>(x, part, M);
        k_prep<false>  <<<64,  256, 0, stream>>>(part, conv_w, EK, cls, M, bp);
        k_bias         <<<8,   256, 0, stream>>>(conv_b, EB, cls, bp, bias);
        k_gemm_fb      <<<2048, 512, 0, stream>>>(x, M, bias, out);
    }
}